// Round 1
// baseline (188.398 us; speedup 1.0000x reference)
//
#include <hip/hip_runtime.h>
#include <math.h>

#define ALPHA 0.7f
#define BETTA 0.3f
#define EPS   1e-8f

__device__ __forceinline__ void row_contrib(float x1, float y1, float z1,
                                            float x2, float y2, float z2,
                                            float& a0, float& a1, float& a2,
                                            float& ac) {
    // ||v1|| and row mask
    float n1n = sqrtf(x1 * x1 + y1 * y1 + z1 * z1);
    float m = (n1n > EPS) ? 1.0f : 0.0f;
    float inv1 = 1.0f / ((n1n > 0.0f) ? n1n : 1.0f);
    float n1x = x1 * inv1, n1y = y1 * inv1, n1z = z1 * inv1;

    // unit(v2)
    float n2n_ = sqrtf(x2 * x2 + y2 * y2 + z2 * z2);
    float inv2 = 1.0f / ((n2n_ > 0.0f) ? n2n_ : 1.0f);
    float u2x = x2 * inv2, u2y = y2 * inv2, u2z = z2 * inv2;

    // cos of angle, clamped; sin(arccos(c)) = sqrt(1-c^2), cos(arccos(c)) = c
    float c = n1x * u2x + n1y * u2y + n1z * u2z;
    c = fminf(1.0f, fmaxf(-1.0f, c));
    float sin_a = sqrtf(fmaxf(0.0f, 1.0f - c * c));
    float cm1 = c - 1.0f;

    // Gram-Schmidt companion n2 = unit(v2 - n1 * <n1,v2>)
    float d = n1x * x2 + n1y * y2 + n1z * z2;
    float wx = x2 - n1x * d, wy = y2 - n1y * d, wz = z2 - n1z * d;
    float wn = sqrtf(wx * wx + wy * wy + wz * wz);
    float invw = 1.0f / ((wn > 0.0f) ? wn : 1.0f);
    float n2x = wx * invw, n2y = wy * invw, n2z = wz * invw;

    float s1 = n1x + n1y + n1z;
    float s2 = n2x + n2y + n2z;

    float tax = sin_a * (n2x * s1 - n1x * s2);
    float tay = sin_a * (n2y * s1 - n1y * s2);
    float taz = sin_a * (n2z * s1 - n1z * s2);

    float tbx = cm1 * (n1x * s1 + n2x * s2);
    float tby = cm1 * (n1y * s1 + n2y * s2);
    float tbz = cm1 * (n1z * s1 + n2z * s2);

    float p0 = ALPHA * tax * tax + BETTA * tbx * tbx;
    float p1 = ALPHA * tay * tay + BETTA * tby * tby;
    float p2 = ALPHA * taz * taz + BETTA * tbz * tbz;

    a0 += p0 * m;
    a1 += p1 * m;
    a2 += p2 * m;
    ac += m;
}

// Each thread handles 4 rows (12 floats = 3 float4 per input, 16B-aligned
// since byte offset = 48*tid). 256 threads/block.
__global__ __launch_bounds__(256) void trl_reduce(const float* __restrict__ v1,
                                                  const float* __restrict__ v2,
                                                  float* __restrict__ ws,
                                                  int n_rows) {
    int tid = blockIdx.x * blockDim.x + threadIdx.x;
    int row0 = tid * 4;

    float a0 = 0.0f, a1 = 0.0f, a2 = 0.0f, ac = 0.0f;

    if (row0 + 3 < n_rows) {
        const float4* p1 = (const float4*)(v1 + (size_t)row0 * 3);
        const float4* p2 = (const float4*)(v2 + (size_t)row0 * 3);
        float4 A0 = p1[0], A1 = p1[1], A2 = p1[2];
        float4 B0 = p2[0], B1 = p2[1], B2 = p2[2];
        row_contrib(A0.x, A0.y, A0.z, B0.x, B0.y, B0.z, a0, a1, a2, ac);
        row_contrib(A0.w, A1.x, A1.y, B0.w, B1.x, B1.y, a0, a1, a2, ac);
        row_contrib(A1.z, A1.w, A2.x, B1.z, B1.w, B2.x, a0, a1, a2, ac);
        row_contrib(A2.y, A2.z, A2.w, B2.y, B2.z, B2.w, a0, a1, a2, ac);
    } else {
        // scalar tail (not hit for N = 2^21, kept for generality)
        for (int r = row0; r < n_rows && r < row0 + 4; ++r) {
            const float* q1 = v1 + (size_t)r * 3;
            const float* q2 = v2 + (size_t)r * 3;
            row_contrib(q1[0], q1[1], q1[2], q2[0], q2[1], q2[2], a0, a1, a2, ac);
        }
    }

    // wave-64 shuffle reduction
    for (int off = 32; off > 0; off >>= 1) {
        a0 += __shfl_down(a0, off, 64);
        a1 += __shfl_down(a1, off, 64);
        a2 += __shfl_down(a2, off, 64);
        ac += __shfl_down(ac, off, 64);
    }

    __shared__ float smem[4][4];  // 4 waves x 4 accumulators
    int lane = threadIdx.x & 63;
    int wave = threadIdx.x >> 6;
    if (lane == 0) {
        smem[wave][0] = a0;
        smem[wave][1] = a1;
        smem[wave][2] = a2;
        smem[wave][3] = ac;
    }
    __syncthreads();
    if (threadIdx.x == 0) {
        float t0 = smem[0][0] + smem[1][0] + smem[2][0] + smem[3][0];
        float t1 = smem[0][1] + smem[1][1] + smem[2][1] + smem[3][1];
        float t2 = smem[0][2] + smem[1][2] + smem[2][2] + smem[3][2];
        float tc = smem[0][3] + smem[1][3] + smem[2][3] + smem[3][3];
        atomicAdd(&ws[0], t0);
        atomicAdd(&ws[1], t1);
        atomicAdd(&ws[2], t2);
        atomicAdd(&ws[3], tc);
    }
}

__global__ void trl_final(const float* __restrict__ ws, float* __restrict__ out) {
    int i = threadIdx.x;
    if (i < 3) {
        float cnt = fmaxf(ws[3], 1.0f);
        float v = ws[i] / cnt;
        // nan_to_num(nan=0, posinf=0.1, neginf=-0.1)
        if (isnan(v)) v = 0.0f;
        else if (isinf(v)) v = (v > 0.0f) ? 0.1f : -0.1f;
        out[i] = v;
    }
}

extern "C" void kernel_launch(void* const* d_in, const int* in_sizes, int n_in,
                              void* d_out, int out_size, void* d_ws, size_t ws_size,
                              hipStream_t stream) {
    const float* v1 = (const float*)d_in[0];
    const float* v2 = (const float*)d_in[1];
    float* out = (float*)d_out;
    float* ws = (float*)d_ws;

    int n_rows = in_sizes[0] / 3;

    // zero the 4-float accumulator workspace (re-poisoned to 0xAA every call)
    hipMemsetAsync(ws, 0, 4 * sizeof(float), stream);

    int groups = (n_rows + 3) / 4;            // rows per thread = 4
    int block = 256;
    int grid = (groups + block - 1) / block;  // 2048 blocks for N=2^21

    trl_reduce<<<grid, block, 0, stream>>>(v1, v2, ws, n_rows);
    trl_final<<<1, 64, 0, stream>>>(ws, out);
}

// Round 2
// 96.503 us; speedup vs baseline: 1.9522x; 1.9522x over previous
//
#include <hip/hip_runtime.h>
#include <math.h>

#define ALPHA 0.7f
#define BETTA 0.3f
#define EPS   1e-8f

__device__ __forceinline__ void row_contrib(float x1, float y1, float z1,
                                            float x2, float y2, float z2,
                                            float& a0, float& a1, float& a2,
                                            float& ac) {
    // squared norm of v1; mask uses ||v1|| > EPS  <=>  q1 > EPS^2
    float q1 = x1 * x1 + y1 * y1 + z1 * z1;
    float m = (q1 > EPS * EPS) ? 1.0f : 0.0f;
    // unit(v1): if norm==0 the vector is 0, so inv=0 reproduces v/1 = 0
    float inv1 = (q1 > 0.0f) ? rsqrtf(q1) : 0.0f;
    float n1x = x1 * inv1, n1y = y1 * inv1, n1z = z1 * inv1;

    // unit(v2)
    float q2 = x2 * x2 + y2 * y2 + z2 * z2;
    float inv2 = (q2 > 0.0f) ? rsqrtf(q2) : 0.0f;
    float u2x = x2 * inv2, u2y = y2 * inv2, u2z = z2 * inv2;

    // cos angle, clamped; sin(arccos(c)) = sqrt(1-c^2), cos(arccos(c)) = c
    float c = n1x * u2x + n1y * u2y + n1z * u2z;
    c = fminf(1.0f, fmaxf(-1.0f, c));
    float sin_a = sqrtf(fmaxf(0.0f, 1.0f - c * c));
    float cm1 = c - 1.0f;

    // Gram-Schmidt companion n2 = unit(v2 - n1 * <n1,v2>)
    float d = n1x * x2 + n1y * y2 + n1z * z2;
    float wx = x2 - n1x * d, wy = y2 - n1y * d, wz = z2 - n1z * d;
    float wq = wx * wx + wy * wy + wz * wz;
    float invw = (wq > 0.0f) ? rsqrtf(wq) : 0.0f;
    float n2x = wx * invw, n2y = wy * invw, n2z = wz * invw;

    float s1 = n1x + n1y + n1z;
    float s2 = n2x + n2y + n2z;

    float tax = sin_a * (n2x * s1 - n1x * s2);
    float tay = sin_a * (n2y * s1 - n1y * s2);
    float taz = sin_a * (n2z * s1 - n1z * s2);

    float tbx = cm1 * (n1x * s1 + n2x * s2);
    float tby = cm1 * (n1y * s1 + n2y * s2);
    float tbz = cm1 * (n1z * s1 + n2z * s2);

    a0 += (ALPHA * tax * tax + BETTA * tbx * tbx) * m;
    a1 += (ALPHA * tay * tay + BETTA * tby * tby) * m;
    a2 += (ALPHA * taz * taz + BETTA * tbz * tbz) * m;
    ac += m;
}

// Stage 1: each thread handles 4 rows (3 float4 per input). Each block writes
// its 4 partial sums to ws (component-major), NO atomics — same-address
// device atomics were serializing at ~15ns each (123us tail in R1).
__global__ __launch_bounds__(256) void trl_reduce(const float* __restrict__ v1,
                                                  const float* __restrict__ v2,
                                                  float* __restrict__ ws,
                                                  int n_rows, int nblocks) {
    int tid = blockIdx.x * blockDim.x + threadIdx.x;
    int row0 = tid * 4;

    float a0 = 0.0f, a1 = 0.0f, a2 = 0.0f, ac = 0.0f;

    if (row0 + 3 < n_rows) {
        const float4* p1 = (const float4*)(v1 + (size_t)row0 * 3);
        const float4* p2 = (const float4*)(v2 + (size_t)row0 * 3);
        float4 A0 = p1[0], A1 = p1[1], A2 = p1[2];
        float4 B0 = p2[0], B1 = p2[1], B2 = p2[2];
        row_contrib(A0.x, A0.y, A0.z, B0.x, B0.y, B0.z, a0, a1, a2, ac);
        row_contrib(A0.w, A1.x, A1.y, B0.w, B1.x, B1.y, a0, a1, a2, ac);
        row_contrib(A1.z, A1.w, A2.x, B1.z, B1.w, B2.x, a0, a1, a2, ac);
        row_contrib(A2.y, A2.z, A2.w, B2.y, B2.z, B2.w, a0, a1, a2, ac);
    } else {
        for (int r = row0; r < n_rows && r < row0 + 4; ++r) {
            const float* q1 = v1 + (size_t)r * 3;
            const float* q2 = v2 + (size_t)r * 3;
            row_contrib(q1[0], q1[1], q1[2], q2[0], q2[1], q2[2], a0, a1, a2, ac);
        }
    }

    // wave-64 shuffle reduction
    for (int off = 32; off > 0; off >>= 1) {
        a0 += __shfl_down(a0, off, 64);
        a1 += __shfl_down(a1, off, 64);
        a2 += __shfl_down(a2, off, 64);
        ac += __shfl_down(ac, off, 64);
    }

    __shared__ float smem[4][4];  // 4 waves x 4 accumulators
    int lane = threadIdx.x & 63;
    int wave = threadIdx.x >> 6;
    if (lane == 0) {
        smem[wave][0] = a0;
        smem[wave][1] = a1;
        smem[wave][2] = a2;
        smem[wave][3] = ac;
    }
    __syncthreads();
    if (threadIdx.x == 0) {
        float t0 = smem[0][0] + smem[1][0] + smem[2][0] + smem[3][0];
        float t1 = smem[0][1] + smem[1][1] + smem[2][1] + smem[3][1];
        float t2 = smem[0][2] + smem[1][2] + smem[2][2] + smem[3][2];
        float tc = smem[0][3] + smem[1][3] + smem[2][3] + smem[3][3];
        // component-major so stage 2 reads coalesced
        ws[0 * (size_t)nblocks + blockIdx.x] = t0;
        ws[1 * (size_t)nblocks + blockIdx.x] = t1;
        ws[2 * (size_t)nblocks + blockIdx.x] = t2;
        ws[3 * (size_t)nblocks + blockIdx.x] = tc;
    }
}

// Stage 2: one block; wave w reduces component w over all block partials.
__global__ __launch_bounds__(256) void trl_final(const float* __restrict__ ws,
                                                 float* __restrict__ out,
                                                 int nblocks) {
    __shared__ float comp[4];
    int lane = threadIdx.x & 63;
    int wave = threadIdx.x >> 6;  // 0..3 -> component
    const float* base = ws + (size_t)wave * nblocks;
    float s = 0.0f;
    for (int i = lane; i < nblocks; i += 64) s += base[i];
    for (int off = 32; off > 0; off >>= 1) s += __shfl_down(s, off, 64);
    if (lane == 0) comp[wave] = s;
    __syncthreads();
    if (threadIdx.x < 3) {
        float cnt = fmaxf(comp[3], 1.0f);
        float v = comp[threadIdx.x] / cnt;
        if (isnan(v)) v = 0.0f;
        else if (isinf(v)) v = (v > 0.0f) ? 0.1f : -0.1f;
        out[threadIdx.x] = v;
    }
}

extern "C" void kernel_launch(void* const* d_in, const int* in_sizes, int n_in,
                              void* d_out, int out_size, void* d_ws, size_t ws_size,
                              hipStream_t stream) {
    const float* v1 = (const float*)d_in[0];
    const float* v2 = (const float*)d_in[1];
    float* out = (float*)d_out;
    float* ws = (float*)d_ws;

    int n_rows = in_sizes[0] / 3;

    int block = 256;
    int groups = (n_rows + 3) / 4;            // rows per thread = 4
    int grid = (groups + block - 1) / block;  // 2048 blocks for N=2^21

    trl_reduce<<<grid, block, 0, stream>>>(v1, v2, ws, n_rows, grid);
    trl_final<<<1, 256, 0, stream>>>(ws, out, grid);
}